// Round 19
// baseline (214.639 us; speedup 1.0000x reference)
//
#include <hip/hip_runtime.h>
#include <stdint.h>

#define NB 32
#define C_ 128
#define H_ 56
#define W_ 56
#define HW 3136
#define KD 384

typedef __attribute__((ext_vector_type(8))) short bf16x8;
typedef __attribute__((ext_vector_type(4))) float f32x4;

__device__ inline uint16_t f2bf(float f) {
    uint32_t u = __float_as_uint(f);
    return (uint16_t)((u + 0x7FFFu + ((u >> 16) & 1u)) >> 16);
}
__device__ inline float bf2f(uint16_t b) {
    return __uint_as_float(((uint32_t)b) << 16);
}

// ---------------------------------------------------------------------------
// P1: x (f32) -> xtp bf16 [n][h][w64][c]  AND  xb bf16 [n][c][h][w64].
// Blocks with n==NB instead run the fused kt+p2 (p10t / ap) prep work.
// ---------------------------------------------------------------------------
__global__ __launch_bounds__(256) void p1_xtp(const float* __restrict__ x,
                                              uint16_t* __restrict__ xtp,
                                              uint16_t* __restrict__ xb,
                                              const float* __restrict__ p10,
                                              const float* __restrict__ p3,
                                              uint16_t* __restrict__ p10t,
                                              uint16_t* __restrict__ ap) {
    const int h = blockIdx.x, n = blockIdx.y;
    const int tid = threadIdx.x;
    if (n == NB) {
        // --- kt body: p10 -> p10t [h][w64][d'] (rows w>=56 zero) ---
        for (int idx = tid; idx < 3072; idx += 256) {
            int w = idx & 63, ch = idx >> 6;
            int dp0 = ch * 8;
            uint32_t pk[4];
#pragma unroll
            for (int j = 0; j < 8; ++j) {
                int dp = dp0 + j;
                int tap = dp >> 7, c2 = dp & 127;
                int dor = 3 * c2 + tap;
                float v = (w < W_) ? p10[(size_t)dor * HW + h * W_ + w] : 0.f;
                uint16_t bb = f2bf(v);
                if (j & 1) pk[j >> 1] |= ((uint32_t)bb) << 16;
                else       pk[j >> 1] = bb;
            }
            *(uint4*)&p10t[((size_t)h * 64 + w) * KD + dp0] = *(const uint4*)pk;
        }
        // --- p2 body: p3 -> ap ---
        for (int i = h * 256 + tid; i < 49152; i += 56 * 256) {
            int c = i / KD, dp = i - c * KD;
            int tap = dp >> 7, c2 = dp & 127;
            ap[i] = f2bf(p3[c * KD + 3 * c2 + tap]);
        }
        return;
    }

    __shared__ uint16_t lt[56][136];
    const int c = tid >> 1, wh = tid & 1;
    const float* xr = &x[(((size_t)n * C_ + c) * H_ + h) * W_ + wh * 28];
    uint32_t pk[14];
#pragma unroll
    for (int q = 0; q < 7; ++q) {
        float4 v = *(const float4*)&xr[q * 4];
        int wb = wh * 28 + q * 4;
        uint16_t b0 = f2bf(v.x), b1 = f2bf(v.y), b2 = f2bf(v.z), b3 = f2bf(v.w);
        lt[wb + 0][c] = b0;
        lt[wb + 1][c] = b1;
        lt[wb + 2][c] = b2;
        lt[wb + 3][c] = b3;
        pk[q * 2]     = (uint32_t)b0 | ((uint32_t)b1 << 16);
        pk[q * 2 + 1] = (uint32_t)b2 | ((uint32_t)b3 << 16);
    }
    {
        uint16_t* xrow = &xb[(((size_t)n * C_ + c) * H_ + h) * 64 + wh * 28];
#pragma unroll
        for (int q = 0; q < 7; ++q)
            *(uint2*)&xrow[q * 4] = make_uint2(pk[q * 2], pk[q * 2 + 1]);
        if (wh == 1) {
            uint4 z = {0, 0, 0, 0};
            *(uint4*)&xrow[28] = z;   // w = 56..63 pad
        }
    }
    __syncthreads();
    const int w = tid >> 2, qc = tid & 3;
    uint16_t* dst = &xtp[((((size_t)n * H_ + h) * 64 + w)) * C_ + qc * 32];
    if (w < 56) {
        const uint32_t* s = (const uint32_t*)&lt[w][qc * 32];
        uint4 a = *(const uint4*)(s);
        uint4 b = *(const uint4*)(s + 4);
        uint4 c4 = *(const uint4*)(s + 8);
        uint4 d4 = *(const uint4*)(s + 12);
        *(uint4*)dst = a;
        *(uint4*)(dst + 8) = b;
        *(uint4*)(dst + 16) = c4;
        *(uint4*)(dst + 24) = d4;
    } else {
        uint4 z = {0, 0, 0, 0};
        *(uint4*)dst = z;
        *(uint4*)(dst + 8) = z;
        *(uint4*)(dst + 16) = z;
        *(uint4*)(dst + 24) = z;
    }
}

// ---------------------------------------------------------------------------
// K1: MFMA -> t3b[n][c][h][w64], w-split (24KB LDS); staging loads batched.
// ---------------------------------------------------------------------------
__global__ __launch_bounds__(256) void k1(const uint16_t* __restrict__ xtp,
                                          const uint16_t* __restrict__ ap,
                                          uint16_t* __restrict__ t3b) {
    __shared__ uint16_t smem[3 * 32 * 128];   // 24 KB; reused as lrow[128][40]
    const int bx = blockIdx.x, n = blockIdx.y, tid = threadIdx.x;
    const int h = bx >> 1, wbase = (bx & 1) << 5;
    const int lane = tid & 63, wid = tid >> 6;
    const int c15 = lane & 15, kq = lane >> 4;

    uint4 vst[6];
#pragma unroll
    for (int i = 0; i < 6; ++i) {
        int t = i * 256 + tid;
        int tap = t >> 9, r = t & 511, w = r >> 4, qp = r & 15;
        int q = qp ^ (w & 7);
        int hh = h + 2 * (tap - 1);
        uint4 v = {0, 0, 0, 0};
        if ((unsigned)hh < (unsigned)H_)
            v = *(const uint4*)&xtp[((((size_t)n * H_ + hh) * 64 + wbase + w)) * C_ + q * 8];
        vst[i] = v;
    }
#pragma unroll
    for (int i = 0; i < 6; ++i) {
        int t = i * 256 + tid;
        int tap = t >> 9, r = t & 511, w = r >> 4, qp = r & 15;
        *(uint4*)&smem[tap * 4096 + w * 128 + qp * 8] = vst[i];
    }
    __syncthreads();

    f32x4 acc[2][2] = {};
    for (int ks = 0; ks < 12; ++ks) {
        int tap = ks >> 2, kk = ks & 3;
        bf16x8 a[2], b[2];
#pragma unroll
        for (int m = 0; m < 2; ++m) {
            int c = wid * 32 + m * 16 + c15;
            a[m] = *(const bf16x8*)&ap[c * KD + ks * 32 + kq * 8];
        }
#pragma unroll
        for (int nt = 0; nt < 2; ++nt) {
            int w = nt * 16 + c15;
            int q = kk * 4 + kq;
            b[nt] = *(const bf16x8*)&smem[tap * 4096 + w * 128 + (q ^ (w & 7)) * 8];
        }
#pragma unroll
        for (int m = 0; m < 2; ++m)
#pragma unroll
            for (int nt = 0; nt < 2; ++nt)
                acc[m][nt] = __builtin_amdgcn_mfma_f32_16x16x32_bf16(a[m], b[nt], acc[m][nt], 0, 0, 0);
    }
    __syncthreads();

    uint16_t* lrow = smem;
#pragma unroll
    for (int m = 0; m < 2; ++m)
#pragma unroll
        for (int nt = 0; nt < 2; ++nt)
#pragma unroll
            for (int r = 0; r < 4; ++r) {
                int c = wid * 32 + m * 16 + kq * 4 + r;
                int wl = nt * 16 + c15;
                lrow[c * 40 + wl] = f2bf(acc[m][nt][r]);
            }
    __syncthreads();

    const uint32_t* lrowd = (const uint32_t*)smem;
    for (int t = tid; t < 512; t += 256) {
        int c = t >> 2, ch = t & 3;
        int m0 = c * 20 + ch * 4;
        uint4 o = make_uint4(lrowd[m0], lrowd[m0 + 1], lrowd[m0 + 2], lrowd[m0 + 3]);
        *(uint4*)&t3b[(((size_t)n * C_ + c) * H_ + h) * 64 + wbase + ch * 8] = o;
    }
}

// ---------------------------------------------------------------------------
// K2 (tap-merged, c-split 4, 2h-per-stage): part16[hc][n][c][dp=384].
// ---------------------------------------------------------------------------
__global__ __launch_bounds__(512) void k2(const uint16_t* __restrict__ xb,
                                          const uint16_t* __restrict__ t3b,
                                          uint16_t* __restrict__ part16) {
    __shared__ uint16_t xs[2][32 * 64];     // 8 KB
    __shared__ uint16_t ts[2][128 * 64];    // 32 KB
    const int bx = blockIdx.x;
    const int hc = bx >> 2, cq = bx & 3;
    const int n = blockIdx.y;
    const int tid = threadIdx.x, lane = tid & 63, wid = tid >> 6;
    const int c15 = lane & 15, kq = lane >> 4;

    f32x4 acc[2][3] = {};
    for (int hr = 0; hr < 8; hr += 2) {
        __syncthreads();
#pragma unroll
        for (int hp = 0; hp < 2; ++hp) {
            const int h = hc * 8 + hr + hp;
            if (tid < 256) {
                int cl = tid >> 3, qp = tid & 7, q = qp ^ (cl & 7);
                uint4 v = *(const uint4*)&xb[(((size_t)n * C_ + cq * 32 + cl) * H_ + h) * 64 + q * 8];
                *(uint4*)&xs[hp][cl * 64 + qp * 8] = v;
            }
#pragma unroll
            for (int i = 0; i < 2; ++i) {
                int t = i * 512 + tid;
                int c2 = t >> 3, qp = t & 7, q = qp ^ (c2 & 7);
                uint4 v = *(const uint4*)&t3b[(((size_t)n * C_ + c2) * H_ + h) * 64 + q * 8];
                *(uint4*)&ts[hp][c2 * 64 + qp * 8] = v;
            }
        }
        __syncthreads();
#pragma unroll
        for (int hp = 0; hp < 2; ++hp) {
#pragma unroll
            for (int ks = 0; ks < 2; ++ks) {
                const int q = ks * 4 + kq;
                bf16x8 a[2];
#pragma unroll
                for (int m = 0; m < 2; ++m) {
                    int cl = m * 16 + c15;
                    a[m] = *(const bf16x8*)&xs[hp][cl * 64 + ((q ^ (cl & 7)) << 3)];
                }
                const int c2 = wid * 16 + c15;
                const int base = c2 * 64;
                const int s7 = c2 & 7;
                uint4 v = *(const uint4*)&ts[hp][base + ((q ^ s7) << 3)];
                uint32_t pv = (q > 0) ? *(const uint32_t*)&ts[hp][base + (((q - 1) ^ s7) << 3) + 6] : 0u;
                uint32_t nx = (q < 7) ? *(const uint32_t*)&ts[hp][base + (((q + 1) ^ s7) << 3)] : 0u;
                uint4 b0, b2;
                b0.x = (v.x << 16) | (pv >> 16);     // tap0: t3[w-1]
                b0.y = (v.y << 16) | (v.x >> 16);
                b0.z = (v.z << 16) | (v.y >> 16);
                b0.w = (v.w << 16) | (v.z >> 16);
                b2.x = (v.y << 16) | (v.x >> 16);    // tap2: t3[w+1]
                b2.y = (v.z << 16) | (v.y >> 16);
                b2.z = (v.w << 16) | (v.z >> 16);
                b2.w = (nx << 16)  | (v.w >> 16);
                bf16x8 bt0 = *(const bf16x8*)&b0;
                bf16x8 bt1 = *(const bf16x8*)&v;
                bf16x8 bt2 = *(const bf16x8*)&b2;
#pragma unroll
                for (int m = 0; m < 2; ++m) {
                    acc[m][0] = __builtin_amdgcn_mfma_f32_16x16x32_bf16(a[m], bt0, acc[m][0], 0, 0, 0);
                    acc[m][1] = __builtin_amdgcn_mfma_f32_16x16x32_bf16(a[m], bt1, acc[m][1], 0, 0, 0);
                    acc[m][2] = __builtin_amdgcn_mfma_f32_16x16x32_bf16(a[m], bt2, acc[m][2], 0, 0, 0);
                }
            }
        }
    }
#pragma unroll
    for (int m = 0; m < 2; ++m)
#pragma unroll
        for (int tap = 0; tap < 3; ++tap)
#pragma unroll
            for (int r = 0; r < 4; ++r) {
                int c = cq * 32 + m * 16 + kq * 4 + r;
                int dp = tap * 128 + wid * 16 + c15;
                part16[((size_t)(hc * NB + n) * C_ + c) * 384 + dp] = f2bf(acc[m][tap][r]);
            }
}

// ---------------------------------------------------------------------------
// KRA: fused kr + ka2 (block owns 4 nc-rows).
// ---------------------------------------------------------------------------
__global__ __launch_bounds__(256) void kra(const uint16_t* __restrict__ part16,
                                           uint16_t* __restrict__ acat) {
    __shared__ uint16_t lds[4][384];
    const int tid = threadIdx.x;
    const int rl = tid >> 6, lane = tid & 63;
    const int nc = blockIdx.x * 4 + rl;
    const float sc = 1.f / 56.f;
#pragma unroll
    for (int j = 0; j < 6; ++j) {
        int dp = j * 64 + lane;
        float s = 0.f;
#pragma unroll
        for (int hc = 0; hc < 7; ++hc)
            s += bf2f(part16[((size_t)hc * NB * C_ + nc) * 384 + dp]);
        uint16_t v = f2bf(s * sc);
        acat[(size_t)nc * 512 + dp] = v;
        lds[rl][dp] = v;
    }
    __syncthreads();
#pragma unroll
    for (int t2 = 0; t2 < 2; ++t2) {
        int t = tid + t2 * 256;
        int r = t >> 7, m = t & 127;
        float s = 0.f;
#pragma unroll
        for (int r3 = 0; r3 < 3; ++r3) {
            int d = m + 128 * r3;
            int q3 = d / 3;
            int dp = (d - q3 * 3) * 128 + q3;
            s += bf2f(lds[r][dp]);
        }
        acat[(size_t)(blockIdx.x * 4 + r) * 512 + 384 + m] = f2bf(s);
    }
}

// ---------------------------------------------------------------------------
// K3: K=512 GEMM (256 thr, 128c x 32w tile, 32KB LDS). t3 section first
// (loads co-issue); softmax without max-subtract (inputs are O(1), exact
// same mathematical softmax, removes serial fmax chain).
// ---------------------------------------------------------------------------
__global__ __launch_bounds__(256, 4) void k3(const uint16_t* __restrict__ xtp,
                                             const uint16_t* __restrict__ t3b,
                                             const uint16_t* __restrict__ acat,
                                             const uint16_t* __restrict__ p10t,
                                             const float* __restrict__ p2,
                                             const float* __restrict__ p5,
                                             float* __restrict__ out) {
    __shared__ uint16_t tsm[32 * 512];  // 32 KB, rows w-local (1024B), XOR-swz
    const int bx = blockIdx.x, n = blockIdx.y, tid = threadIdx.x;
    const int h = bx >> 1, wbase = (bx & 1) << 5;
    const int lane = tid & 63, wid = tid >> 6;

    // ---- rows 384..511 first: p5*t3; thread = (c2f 0..127, w-half 0..1) ----
    {
        const int c2f = tid >> 1;
        const int whl = (tid & 1) << 4;    // local w 0..15 / 16..31
        const uint16_t* t3r = &t3b[(((size_t)n * C_ + c2f) * H_ + h) * 64 + wbase + whl];
        const int qf = 48 + (c2f >> 3);
        const int cf7 = c2f & 7;
#pragma unroll
        for (int g = 0; g < 2; ++g) {
            bf16x8 tv = *(const bf16x8*)&t3r[g * 8];
#pragma unroll
            for (int j = 0; j < 8; ++j) {
                int wl = whl + g * 8 + j;
                int wwg = wbase + wl;
                float p5v = (wwg < W_) ? p5[h * W_ + wwg] : 0.f;
                tsm[wl * 512 + ((qf ^ (wl & 7)) << 3) + cf7] = f2bf(p5v * bf2f((uint16_t)tv[j]));
            }
        }
    }

    // ---- build rows 0..383: thread = (w-local 0..31, seg 0..7) ----
    {
        const int w = tid & 31, seg = tid >> 5;
        const int wg = wbase + w;
        const int wsw = w & 7;
        float p2v[3];
#pragma unroll
        for (int tap = 0; tap < 3; ++tap)
            p2v[tap] = (wg < W_) ? p2[tap * W_ + wg] : 0.f;
        const size_t xrow = ((size_t)n * H_ + h) * 64;
        const int wgm2 = (wg >= 2) ? wg - 2 : 0;
        const int wgp2 = (wg + 2 < 64) ? wg + 2 : 63;   // rows >=56 are zeros
        const int hh0 = h - 2, hh2 = h + 2;
        const bool hok0 = (hh0 >= 0), hok2 = (hh2 < H_);
        const size_t xrow0 = ((size_t)n * H_ + (hok0 ? hh0 : h)) * 64;
        const size_t xrow2 = ((size_t)n * H_ + (hok2 ? hh2 : h)) * 64;
        const float p2e0 = hok0 ? p2v[0] : 0.f;
        const float p2e2 = hok2 ? p2v[2] : 0.f;
        const uint16_t* pt = &p10t[((size_t)h * 64 + wg) * KD];

        bf16x8 Lxh[2], Lxm[2], Lxp[2], Lx0[2], Lx2[2], Lp0[2], Lp1[2], Lp2[2];
#pragma unroll
        for (int s = 0; s < 2; ++s) {
            const int c2b = (seg + s * 8) * 8;
            Lxh[s] = *(const bf16x8*)&xtp[(xrow + wg) * C_ + c2b];
            Lxm[s] = *(const bf16x8*)&xtp[(xrow + wgm2) * C_ + c2b];
            Lxp[s] = *(const bf16x8*)&xtp[(xrow + wgp2) * C_ + c2b];
            Lx0[s] = *(const bf16x8*)&xtp[(xrow0 + wg) * C_ + c2b];
            Lx2[s] = *(const bf16x8*)&xtp[(xrow2 + wg) * C_ + c2b];
            Lp0[s] = *(const bf16x8*)&pt[c2b];
            Lp1[s] = *(const bf16x8*)&pt[128 + c2b];
            Lp2[s] = *(const bf16x8*)&pt[256 + c2b];
        }
#pragma unroll
        for (int s = 0; s < 2; ++s) {
            const int c2b = (seg + s * 8) * 8;
            float sm[3][8];
#pragma unroll
            for (int j = 0; j < 8; ++j) {
                float a1 = bf2f((uint16_t)Lxh[s][j]);
                float a0 = (wg >= 2) ? bf2f((uint16_t)Lxm[s][j]) : 0.f;
                float a2 = bf2f((uint16_t)Lxp[s][j]);
                float e0 = __expf(a0), e1 = __expf(a1), e2 = __expf(a2);
                float rs = 1.f / (e0 + e1 + e2);
                sm[0][j] = e0 * rs; sm[1][j] = e1 * rs; sm[2][j] = e2 * rs;
            }
            uint32_t pk0[4], pk1[4], pk2[4];
#pragma unroll
            for (int j = 0; j < 8; ++j) {
                float v0 = -(p2e0   * bf2f((uint16_t)Lx0[s][j]) + bf2f((uint16_t)Lp0[s][j]) * sm[0][j]);
                float v1 = -(p2v[1] * bf2f((uint16_t)Lxh[s][j]) + bf2f((uint16_t)Lp1[s][j]) * sm[1][j]);
                float v2 = -(p2e2   * bf2f((uint16_t)Lx2[s][j]) + bf2f((uint16_t)Lp2[s][j]) * sm[2][j]);
                uint16_t b0 = f2bf(v0), b1 = f2bf(v1), b2 = f2bf(v2);
                if (j & 1) { pk0[j >> 1] |= ((uint32_t)b0) << 16;
                             pk1[j >> 1] |= ((uint32_t)b1) << 16;
                             pk2[j >> 1] |= ((uint32_t)b2) << 16; }
                else       { pk0[j >> 1] = b0; pk1[j >> 1] = b1; pk2[j >> 1] = b2; }
            }
            int q0 = (c2b) >> 3, q1 = (128 + c2b) >> 3, q2 = (256 + c2b) >> 3;
            *(uint4*)&tsm[w * 512 + ((q0 ^ wsw) << 3)] = *(const uint4*)pk0;
            *(uint4*)&tsm[w * 512 + ((q1 ^ wsw) << 3)] = *(const uint4*)pk1;
            *(uint4*)&tsm[w * 512 + ((q2 ^ wsw) << 3)] = *(const uint4*)pk2;
        }
    }
    __syncthreads();

    // ---- 16-kstep GEMM: wave wm owns c-band [wm*32, wm*32+32) ----
    const int wm = wid;
    f32x4 acc[2][2] = {};
    for (int ks = 0; ks < 16; ++ks) {
        bf16x8 a[2], b[2];
#pragma unroll
        for (int m = 0; m < 2; ++m) {
            int c = wm * 32 + m * 16 + (lane & 15);
            a[m] = *(const bf16x8*)&acat[((size_t)n * C_ + c) * 512 + ks * 32 + (lane >> 4) * 8];
        }
#pragma unroll
        for (int nt = 0; nt < 2; ++nt) {
            int wl = nt * 16 + (lane & 15);
            int q = ks * 4 + (lane >> 4);
            b[nt] = *(const bf16x8*)&tsm[wl * 512 + ((q ^ (wl & 7)) << 3)];
        }
#pragma unroll
        for (int m = 0; m < 2; ++m)
#pragma unroll
            for (int nt = 0; nt < 2; ++nt)
                acc[m][nt] = __builtin_amdgcn_mfma_f32_16x16x32_bf16(a[m], b[nt], acc[m][nt], 0, 0, 0);
    }

    const float s = 0.05103103630798287f;  // 1/sqrt(384)
#pragma unroll
    for (int m = 0; m < 2; ++m)
#pragma unroll
        for (int nt = 0; nt < 2; ++nt) {
            int wwg = wbase + nt * 16 + (lane & 15);
            if (wwg < W_) {
                int c = wm * 32 + m * 16 + (lane >> 4) * 4;
                float* dst = &out[(((size_t)n * C_ + c) * H_ + h) * W_ + wwg];
#pragma unroll
                for (int r = 0; r < 4; ++r) dst[(size_t)r * HW] = acc[m][nt][r] * s;
            }
        }
}

extern "C" void kernel_launch(void* const* d_in, const int* in_sizes, int n_in,
                              void* d_out, int out_size, void* d_ws, size_t ws_size,
                              hipStream_t stream) {
    const float* x   = (const float*)d_in[0];
    const float* p2  = (const float*)d_in[1];
    const float* p3  = (const float*)d_in[2];
    const float* p5  = (const float*)d_in[3];
    const float* p10 = (const float*)d_in[4];
    float* out = (float*)d_out;

    uint8_t* w8 = (uint8_t*)d_ws;
    uint16_t* t3b    = (uint16_t*)(w8);                // 29,360,128 B (live to end)
    uint16_t* ap     = (uint16_t*)(w8 + 29360128);     //     98,304 B
    uint16_t* xtp    = (uint16_t*)(w8 + 29458432);     // 29,360,128 B (live to end)
    uint16_t* xb     = (uint16_t*)(w8 + 58818560);     // 29,360,128 B (p1 -> k2)
    uint16_t* part16 = (uint16_t*)(w8 + 88178688);     // 22,020,096 B (k2 -> kra)
    uint16_t* acat   = (uint16_t*)(w8 + 110198784);    //  4,194,304 B
    uint16_t* p10t   = (uint16_t*)(w8 + 114393088);    //  2,752,512 B (end 117,145,600)

    p1_xtp<<<dim3(H_, NB + 1), 256, 0, stream>>>(x, xtp, xb, p10, p3, p10t, ap);
    k1<<<dim3(112, NB), 256, 0, stream>>>(xtp, ap, t3b);
    k2<<<dim3(28, NB), 512, 0, stream>>>(xb, t3b, part16);
    kra<<<dim3(1024), 256, 0, stream>>>(part16, acat);
    k3<<<dim3(112, NB), 256, 0, stream>>>(xtp, t3b, acat, p10t, p2, p5, out);
}

// Round 20
// 209.700 us; speedup vs baseline: 1.0236x; 1.0236x over previous
//
#include <hip/hip_runtime.h>
#include <stdint.h>

#define NB 32
#define C_ 128
#define H_ 56
#define W_ 56
#define HW 3136
#define KD 384

typedef __attribute__((ext_vector_type(8))) short bf16x8;
typedef __attribute__((ext_vector_type(4))) float f32x4;

__device__ inline uint16_t f2bf(float f) {
    uint32_t u = __float_as_uint(f);
    return (uint16_t)((u + 0x7FFFu + ((u >> 16) & 1u)) >> 16);
}
__device__ inline float bf2f(uint16_t b) {
    return __uint_as_float(((uint32_t)b) << 16);
}

// ---------------------------------------------------------------------------
// P1: x (f32) -> xtp bf16 [n][h][w64][c]  AND  xb bf16 [n][c][h][w64].
// Blocks with n==NB instead run the fused kt+p2 (p10t / ap) prep work.
// ---------------------------------------------------------------------------
__global__ __launch_bounds__(256) void p1_xtp(const float* __restrict__ x,
                                              uint16_t* __restrict__ xtp,
                                              uint16_t* __restrict__ xb,
                                              const float* __restrict__ p10,
                                              const float* __restrict__ p3,
                                              uint16_t* __restrict__ p10t,
                                              uint16_t* __restrict__ ap) {
    const int h = blockIdx.x, n = blockIdx.y;
    const int tid = threadIdx.x;
    if (n == NB) {
        for (int idx = tid; idx < 3072; idx += 256) {
            int w = idx & 63, ch = idx >> 6;
            int dp0 = ch * 8;
            uint32_t pk[4];
#pragma unroll
            for (int j = 0; j < 8; ++j) {
                int dp = dp0 + j;
                int tap = dp >> 7, c2 = dp & 127;
                int dor = 3 * c2 + tap;
                float v = (w < W_) ? p10[(size_t)dor * HW + h * W_ + w] : 0.f;
                uint16_t bb = f2bf(v);
                if (j & 1) pk[j >> 1] |= ((uint32_t)bb) << 16;
                else       pk[j >> 1] = bb;
            }
            *(uint4*)&p10t[((size_t)h * 64 + w) * KD + dp0] = *(const uint4*)pk;
        }
        for (int i = h * 256 + tid; i < 49152; i += 56 * 256) {
            int c = i / KD, dp = i - c * KD;
            int tap = dp >> 7, c2 = dp & 127;
            ap[i] = f2bf(p3[c * KD + 3 * c2 + tap]);
        }
        return;
    }

    __shared__ uint16_t lt[56][136];
    const int c = tid >> 1, wh = tid & 1;
    const float* xr = &x[(((size_t)n * C_ + c) * H_ + h) * W_ + wh * 28];
    uint32_t pk[14];
#pragma unroll
    for (int q = 0; q < 7; ++q) {
        float4 v = *(const float4*)&xr[q * 4];
        int wb = wh * 28 + q * 4;
        uint16_t b0 = f2bf(v.x), b1 = f2bf(v.y), b2 = f2bf(v.z), b3 = f2bf(v.w);
        lt[wb + 0][c] = b0;
        lt[wb + 1][c] = b1;
        lt[wb + 2][c] = b2;
        lt[wb + 3][c] = b3;
        pk[q * 2]     = (uint32_t)b0 | ((uint32_t)b1 << 16);
        pk[q * 2 + 1] = (uint32_t)b2 | ((uint32_t)b3 << 16);
    }
    {
        uint16_t* xrow = &xb[(((size_t)n * C_ + c) * H_ + h) * 64 + wh * 28];
#pragma unroll
        for (int q = 0; q < 7; ++q)
            *(uint2*)&xrow[q * 4] = make_uint2(pk[q * 2], pk[q * 2 + 1]);
        if (wh == 1) {
            uint4 z = {0, 0, 0, 0};
            *(uint4*)&xrow[28] = z;   // w = 56..63 pad
        }
    }
    __syncthreads();
    const int w = tid >> 2, qc = tid & 3;
    uint16_t* dst = &xtp[((((size_t)n * H_ + h) * 64 + w)) * C_ + qc * 32];
    if (w < 56) {
        const uint32_t* s = (const uint32_t*)&lt[w][qc * 32];
        uint4 a = *(const uint4*)(s);
        uint4 b = *(const uint4*)(s + 4);
        uint4 c4 = *(const uint4*)(s + 8);
        uint4 d4 = *(const uint4*)(s + 12);
        *(uint4*)dst = a;
        *(uint4*)(dst + 8) = b;
        *(uint4*)(dst + 16) = c4;
        *(uint4*)(dst + 24) = d4;
    } else {
        uint4 z = {0, 0, 0, 0};
        *(uint4*)dst = z;
        *(uint4*)(dst + 8) = z;
        *(uint4*)(dst + 16) = z;
        *(uint4*)(dst + 24) = z;
    }
}

// ---------------------------------------------------------------------------
// K1: MFMA -> t3b[n][c][h][w64], w-split (24KB LDS); staging loads batched.
// ---------------------------------------------------------------------------
__global__ __launch_bounds__(256) void k1(const uint16_t* __restrict__ xtp,
                                          const uint16_t* __restrict__ ap,
                                          uint16_t* __restrict__ t3b) {
    __shared__ uint16_t smem[3 * 32 * 128];   // 24 KB; reused as lrow[128][40]
    const int bx = blockIdx.x, n = blockIdx.y, tid = threadIdx.x;
    const int h = bx >> 1, wbase = (bx & 1) << 5;
    const int lane = tid & 63, wid = tid >> 6;
    const int c15 = lane & 15, kq = lane >> 4;

    uint4 vst[6];
#pragma unroll
    for (int i = 0; i < 6; ++i) {
        int t = i * 256 + tid;
        int tap = t >> 9, r = t & 511, w = r >> 4, qp = r & 15;
        int q = qp ^ (w & 7);
        int hh = h + 2 * (tap - 1);
        uint4 v = {0, 0, 0, 0};
        if ((unsigned)hh < (unsigned)H_)
            v = *(const uint4*)&xtp[((((size_t)n * H_ + hh) * 64 + wbase + w)) * C_ + q * 8];
        vst[i] = v;
    }
#pragma unroll
    for (int i = 0; i < 6; ++i) {
        int t = i * 256 + tid;
        int tap = t >> 9, r = t & 511, w = r >> 4, qp = r & 15;
        *(uint4*)&smem[tap * 4096 + w * 128 + qp * 8] = vst[i];
    }
    __syncthreads();

    f32x4 acc[2][2] = {};
    for (int ks = 0; ks < 12; ++ks) {
        int tap = ks >> 2, kk = ks & 3;
        bf16x8 a[2], b[2];
#pragma unroll
        for (int m = 0; m < 2; ++m) {
            int c = wid * 32 + m * 16 + c15;
            a[m] = *(const bf16x8*)&ap[c * KD + ks * 32 + kq * 8];
        }
#pragma unroll
        for (int nt = 0; nt < 2; ++nt) {
            int w = nt * 16 + c15;
            int q = kk * 4 + kq;
            b[nt] = *(const bf16x8*)&smem[tap * 4096 + w * 128 + (q ^ (w & 7)) * 8];
        }
#pragma unroll
        for (int m = 0; m < 2; ++m)
#pragma unroll
            for (int nt = 0; nt < 2; ++nt)
                acc[m][nt] = __builtin_amdgcn_mfma_f32_16x16x32_bf16(a[m], b[nt], acc[m][nt], 0, 0, 0);
    }
    __syncthreads();

    uint16_t* lrow = smem;
#pragma unroll
    for (int m = 0; m < 2; ++m)
#pragma unroll
        for (int nt = 0; nt < 2; ++nt)
#pragma unroll
            for (int r = 0; r < 4; ++r) {
                int c = wid * 32 + m * 16 + kq * 4 + r;
                int wl = nt * 16 + c15;
                lrow[c * 40 + wl] = f2bf(acc[m][nt][r]);
            }
    __syncthreads();

    const uint32_t* lrowd = (const uint32_t*)smem;
    for (int t = tid; t < 512; t += 256) {
        int c = t >> 2, ch = t & 3;
        int m0 = c * 20 + ch * 4;
        uint4 o = make_uint4(lrowd[m0], lrowd[m0 + 1], lrowd[m0 + 2], lrowd[m0 + 3]);
        *(uint4*)&t3b[(((size_t)n * C_ + c) * H_ + h) * 64 + wbase + ch * 8] = o;
    }
}

// ---------------------------------------------------------------------------
// K2 (tap-merged, c-split 4, 2h-per-stage): part16[hc][n][c][dp=384].
// ---------------------------------------------------------------------------
__global__ __launch_bounds__(512) void k2(const uint16_t* __restrict__ xb,
                                          const uint16_t* __restrict__ t3b,
                                          uint16_t* __restrict__ part16) {
    __shared__ uint16_t xs[2][32 * 64];     // 8 KB
    __shared__ uint16_t ts[2][128 * 64];    // 32 KB
    const int bx = blockIdx.x;
    const int hc = bx >> 2, cq = bx & 3;
    const int n = blockIdx.y;
    const int tid = threadIdx.x, lane = tid & 63, wid = tid >> 6;
    const int c15 = lane & 15, kq = lane >> 4;

    f32x4 acc[2][3] = {};
    for (int hr = 0; hr < 8; hr += 2) {
        __syncthreads();
#pragma unroll
        for (int hp = 0; hp < 2; ++hp) {
            const int h = hc * 8 + hr + hp;
            if (tid < 256) {
                int cl = tid >> 3, qp = tid & 7, q = qp ^ (cl & 7);
                uint4 v = *(const uint4*)&xb[(((size_t)n * C_ + cq * 32 + cl) * H_ + h) * 64 + q * 8];
                *(uint4*)&xs[hp][cl * 64 + qp * 8] = v;
            }
#pragma unroll
            for (int i = 0; i < 2; ++i) {
                int t = i * 512 + tid;
                int c2 = t >> 3, qp = t & 7, q = qp ^ (c2 & 7);
                uint4 v = *(const uint4*)&t3b[(((size_t)n * C_ + c2) * H_ + h) * 64 + q * 8];
                *(uint4*)&ts[hp][c2 * 64 + qp * 8] = v;
            }
        }
        __syncthreads();
#pragma unroll
        for (int hp = 0; hp < 2; ++hp) {
#pragma unroll
            for (int ks = 0; ks < 2; ++ks) {
                const int q = ks * 4 + kq;
                bf16x8 a[2];
#pragma unroll
                for (int m = 0; m < 2; ++m) {
                    int cl = m * 16 + c15;
                    a[m] = *(const bf16x8*)&xs[hp][cl * 64 + ((q ^ (cl & 7)) << 3)];
                }
                const int c2 = wid * 16 + c15;
                const int base = c2 * 64;
                const int s7 = c2 & 7;
                uint4 v = *(const uint4*)&ts[hp][base + ((q ^ s7) << 3)];
                uint32_t pv = (q > 0) ? *(const uint32_t*)&ts[hp][base + (((q - 1) ^ s7) << 3) + 6] : 0u;
                uint32_t nx = (q < 7) ? *(const uint32_t*)&ts[hp][base + (((q + 1) ^ s7) << 3)] : 0u;
                uint4 b0, b2;
                b0.x = (v.x << 16) | (pv >> 16);     // tap0: t3[w-1]
                b0.y = (v.y << 16) | (v.x >> 16);
                b0.z = (v.z << 16) | (v.y >> 16);
                b0.w = (v.w << 16) | (v.z >> 16);
                b2.x = (v.y << 16) | (v.x >> 16);    // tap2: t3[w+1]
                b2.y = (v.z << 16) | (v.y >> 16);
                b2.z = (v.w << 16) | (v.z >> 16);
                b2.w = (nx << 16)  | (v.w >> 16);
                bf16x8 bt0 = *(const bf16x8*)&b0;
                bf16x8 bt1 = *(const bf16x8*)&v;
                bf16x8 bt2 = *(const bf16x8*)&b2;
#pragma unroll
                for (int m = 0; m < 2; ++m) {
                    acc[m][0] = __builtin_amdgcn_mfma_f32_16x16x32_bf16(a[m], bt0, acc[m][0], 0, 0, 0);
                    acc[m][1] = __builtin_amdgcn_mfma_f32_16x16x32_bf16(a[m], bt1, acc[m][1], 0, 0, 0);
                    acc[m][2] = __builtin_amdgcn_mfma_f32_16x16x32_bf16(a[m], bt2, acc[m][2], 0, 0, 0);
                }
            }
        }
    }
#pragma unroll
    for (int m = 0; m < 2; ++m)
#pragma unroll
        for (int tap = 0; tap < 3; ++tap)
#pragma unroll
            for (int r = 0; r < 4; ++r) {
                int c = cq * 32 + m * 16 + kq * 4 + r;
                int dp = tap * 128 + wid * 16 + c15;
                part16[((size_t)(hc * NB + n) * C_ + c) * 384 + dp] = f2bf(acc[m][tap][r]);
            }
}

// ---------------------------------------------------------------------------
// KRA: fused kr + ka2 (block owns 4 nc-rows).
// ---------------------------------------------------------------------------
__global__ __launch_bounds__(256) void kra(const uint16_t* __restrict__ part16,
                                           uint16_t* __restrict__ acat) {
    __shared__ uint16_t lds[4][384];
    const int tid = threadIdx.x;
    const int rl = tid >> 6, lane = tid & 63;
    const int nc = blockIdx.x * 4 + rl;
    const float sc = 1.f / 56.f;
#pragma unroll
    for (int j = 0; j < 6; ++j) {
        int dp = j * 64 + lane;
        float s = 0.f;
#pragma unroll
        for (int hc = 0; hc < 7; ++hc)
            s += bf2f(part16[((size_t)hc * NB * C_ + nc) * 384 + dp]);
        uint16_t v = f2bf(s * sc);
        acat[(size_t)nc * 512 + dp] = v;
        lds[rl][dp] = v;
    }
    __syncthreads();
#pragma unroll
    for (int t2 = 0; t2 < 2; ++t2) {
        int t = tid + t2 * 256;
        int r = t >> 7, m = t & 127;
        float s = 0.f;
#pragma unroll
        for (int r3 = 0; r3 < 3; ++r3) {
            int d = m + 128 * r3;
            int q3 = d / 3;
            int dp = (d - q3 * 3) * 128 + q3;
            s += bf2f(lds[r][dp]);
        }
        acat[(size_t)(blockIdx.x * 4 + r) * 512 + 384 + m] = f2bf(s);
    }
}

// ---------------------------------------------------------------------------
// K3: K=512 GEMM (256 thr, 128c x 32w tile, 32KB LDS). r18 form: build first,
// all 16 B-build vectors preloaded, max-subtract softmax (measured-best 98us).
// ---------------------------------------------------------------------------
__global__ __launch_bounds__(256, 4) void k3(const uint16_t* __restrict__ xtp,
                                             const uint16_t* __restrict__ t3b,
                                             const uint16_t* __restrict__ acat,
                                             const uint16_t* __restrict__ p10t,
                                             const float* __restrict__ p2,
                                             const float* __restrict__ p5,
                                             float* __restrict__ out) {
    __shared__ uint16_t tsm[32 * 512];  // 32 KB, rows w-local (1024B), XOR-swz
    const int bx = blockIdx.x, n = blockIdx.y, tid = threadIdx.x;
    const int h = bx >> 1, wbase = (bx & 1) << 5;
    const int lane = tid & 63, wid = tid >> 6;

    // ---- build rows 0..383: thread = (w-local 0..31, seg 0..7) ----
    {
        const int w = tid & 31, seg = tid >> 5;
        const int wg = wbase + w;
        const int wsw = w & 7;
        float p2v[3];
#pragma unroll
        for (int tap = 0; tap < 3; ++tap)
            p2v[tap] = (wg < W_) ? p2[tap * W_ + wg] : 0.f;
        const size_t xrow = ((size_t)n * H_ + h) * 64;
        const int wgm2 = (wg >= 2) ? wg - 2 : 0;
        const int wgp2 = (wg + 2 < 64) ? wg + 2 : 63;   // rows >=56 are zeros
        const int hh0 = h - 2, hh2 = h + 2;
        const bool hok0 = (hh0 >= 0), hok2 = (hh2 < H_);
        const size_t xrow0 = ((size_t)n * H_ + (hok0 ? hh0 : h)) * 64;
        const size_t xrow2 = ((size_t)n * H_ + (hok2 ? hh2 : h)) * 64;
        const float p2e0 = hok0 ? p2v[0] : 0.f;
        const float p2e2 = hok2 ? p2v[2] : 0.f;
        const uint16_t* pt = &p10t[((size_t)h * 64 + wg) * KD];

        bf16x8 Lxh[2], Lxm[2], Lxp[2], Lx0[2], Lx2[2], Lp0[2], Lp1[2], Lp2[2];
#pragma unroll
        for (int s = 0; s < 2; ++s) {
            const int c2b = (seg + s * 8) * 8;
            Lxh[s] = *(const bf16x8*)&xtp[(xrow + wg) * C_ + c2b];
            Lxm[s] = *(const bf16x8*)&xtp[(xrow + wgm2) * C_ + c2b];
            Lxp[s] = *(const bf16x8*)&xtp[(xrow + wgp2) * C_ + c2b];
            Lx0[s] = *(const bf16x8*)&xtp[(xrow0 + wg) * C_ + c2b];
            Lx2[s] = *(const bf16x8*)&xtp[(xrow2 + wg) * C_ + c2b];
            Lp0[s] = *(const bf16x8*)&pt[c2b];
            Lp1[s] = *(const bf16x8*)&pt[128 + c2b];
            Lp2[s] = *(const bf16x8*)&pt[256 + c2b];
        }
#pragma unroll
        for (int s = 0; s < 2; ++s) {
            const int c2b = (seg + s * 8) * 8;
            float sm[3][8];
#pragma unroll
            for (int j = 0; j < 8; ++j) {
                float a1 = bf2f((uint16_t)Lxh[s][j]);
                float a0 = (wg >= 2) ? bf2f((uint16_t)Lxm[s][j]) : 0.f;
                float a2 = bf2f((uint16_t)Lxp[s][j]);
                float mx = fmaxf(a0, fmaxf(a1, a2));
                float e0 = __expf(a0 - mx), e1 = __expf(a1 - mx), e2 = __expf(a2 - mx);
                float rs = 1.f / (e0 + e1 + e2);
                sm[0][j] = e0 * rs; sm[1][j] = e1 * rs; sm[2][j] = e2 * rs;
            }
            uint32_t pk0[4], pk1[4], pk2[4];
#pragma unroll
            for (int j = 0; j < 8; ++j) {
                float v0 = -(p2e0   * bf2f((uint16_t)Lx0[s][j]) + bf2f((uint16_t)Lp0[s][j]) * sm[0][j]);
                float v1 = -(p2v[1] * bf2f((uint16_t)Lxh[s][j]) + bf2f((uint16_t)Lp1[s][j]) * sm[1][j]);
                float v2 = -(p2e2   * bf2f((uint16_t)Lx2[s][j]) + bf2f((uint16_t)Lp2[s][j]) * sm[2][j]);
                uint16_t b0 = f2bf(v0), b1 = f2bf(v1), b2 = f2bf(v2);
                if (j & 1) { pk0[j >> 1] |= ((uint32_t)b0) << 16;
                             pk1[j >> 1] |= ((uint32_t)b1) << 16;
                             pk2[j >> 1] |= ((uint32_t)b2) << 16; }
                else       { pk0[j >> 1] = b0; pk1[j >> 1] = b1; pk2[j >> 1] = b2; }
            }
            int q0 = (c2b) >> 3, q1 = (128 + c2b) >> 3, q2 = (256 + c2b) >> 3;
            *(uint4*)&tsm[w * 512 + ((q0 ^ wsw) << 3)] = *(const uint4*)pk0;
            *(uint4*)&tsm[w * 512 + ((q1 ^ wsw) << 3)] = *(const uint4*)pk1;
            *(uint4*)&tsm[w * 512 + ((q2 ^ wsw) << 3)] = *(const uint4*)pk2;
        }
    }

    // ---- rows 384..511: p5*t3; thread = (c2f 0..127, w-half 0..1) ----
    {
        const int c2f = tid >> 1;
        const int whl = (tid & 1) << 4;    // local w 0..15 / 16..31
        const uint16_t* t3r = &t3b[(((size_t)n * C_ + c2f) * H_ + h) * 64 + wbase + whl];
        const int qf = 48 + (c2f >> 3);
        const int cf7 = c2f & 7;
#pragma unroll
        for (int g = 0; g < 2; ++g) {
            bf16x8 tv = *(const bf16x8*)&t3r[g * 8];
#pragma unroll
            for (int j = 0; j < 8; ++j) {
                int wl = whl + g * 8 + j;
                int wwg = wbase + wl;
                float p5v = (wwg < W_) ? p5[h * W_ + wwg] : 0.f;
                tsm[wl * 512 + ((qf ^ (wl & 7)) << 3) + cf7] = f2bf(p5v * bf2f((uint16_t)tv[j]));
            }
        }
    }
    __syncthreads();

    // ---- 16-kstep GEMM: wave wm owns c-band [wm*32, wm*32+32) ----
    const int wm = wid;
    f32x4 acc[2][2] = {};
    for (int ks = 0; ks < 16; ++ks) {
        bf16x8 a[2], b[2];
#pragma unroll
        for (int m = 0; m < 2; ++m) {
            int c = wm * 32 + m * 16 + (lane & 15);
            a[m] = *(const bf16x8*)&acat[((size_t)n * C_ + c) * 512 + ks * 32 + (lane >> 4) * 8];
        }
#pragma unroll
        for (int nt = 0; nt < 2; ++nt) {
            int wl = nt * 16 + (lane & 15);
            int q = ks * 4 + (lane >> 4);
            b[nt] = *(const bf16x8*)&tsm[wl * 512 + ((q ^ (wl & 7)) << 3)];
        }
#pragma unroll
        for (int m = 0; m < 2; ++m)
#pragma unroll
            for (int nt = 0; nt < 2; ++nt)
                acc[m][nt] = __builtin_amdgcn_mfma_f32_16x16x32_bf16(a[m], b[nt], acc[m][nt], 0, 0, 0);
    }

    const float s = 0.05103103630798287f;  // 1/sqrt(384)
#pragma unroll
    for (int m = 0; m < 2; ++m)
#pragma unroll
        for (int nt = 0; nt < 2; ++nt) {
            int wwg = wbase + nt * 16 + (lane & 15);
            if (wwg < W_) {
                int c = wm * 32 + m * 16 + (lane >> 4) * 4;
                float* dst = &out[(((size_t)n * C_ + c) * H_ + h) * W_ + wwg];
#pragma unroll
                for (int r = 0; r < 4; ++r) dst[(size_t)r * HW] = acc[m][nt][r] * s;
            }
        }
}

extern "C" void kernel_launch(void* const* d_in, const int* in_sizes, int n_in,
                              void* d_out, int out_size, void* d_ws, size_t ws_size,
                              hipStream_t stream) {
    const float* x   = (const float*)d_in[0];
    const float* p2  = (const float*)d_in[1];
    const float* p3  = (const float*)d_in[2];
    const float* p5  = (const float*)d_in[3];
    const float* p10 = (const float*)d_in[4];
    float* out = (float*)d_out;

    uint8_t* w8 = (uint8_t*)d_ws;
    uint16_t* t3b    = (uint16_t*)(w8);                // 29,360,128 B (live to end)
    uint16_t* ap     = (uint16_t*)(w8 + 29360128);     //     98,304 B
    uint16_t* xtp    = (uint16_t*)(w8 + 29458432);     // 29,360,128 B (live to end)
    uint16_t* xb     = (uint16_t*)(w8 + 58818560);     // 29,360,128 B (p1 -> k2)
    uint16_t* part16 = (uint16_t*)(w8 + 88178688);     // 22,020,096 B (k2 -> kra)
    uint16_t* acat   = (uint16_t*)(w8 + 110198784);    //  4,194,304 B
    uint16_t* p10t   = (uint16_t*)(w8 + 114393088);    //  2,752,512 B (end 117,145,600)

    p1_xtp<<<dim3(H_, NB + 1), 256, 0, stream>>>(x, xtp, xb, p10, p3, p10t, ap);
    k1<<<dim3(112, NB), 256, 0, stream>>>(xtp, ap, t3b);
    k2<<<dim3(28, NB), 512, 0, stream>>>(xb, t3b, part16);
    kra<<<dim3(1024), 256, 0, stream>>>(part16, acat);
    k3<<<dim3(112, NB), 256, 0, stream>>>(xtp, t3b, acat, p10t, p2, p5, out);
}